// Round 1
// baseline (107.598 us; speedup 1.0000x reference)
//
#include <hip/hip_runtime.h>
#include <math.h>

#define K_DIM 2048
#define E_DIM 64
#define BM 32
#define KC 32

__global__ __launch_bounds__(256, 2) void top2gating_kernel(
    const float* __restrict__ x,
    const float* __restrict__ w,
    float* __restrict__ out,
    int M)
{
    __shared__ float xs[BM][KC];         // 4 KB   x chunk  [row][kk]
    __shared__ float ws[KC][E_DIM];      // 8 KB   w chunk transposed [kk][e]
    __shared__ float lg[BM][E_DIM + 1];  // 8.1 KB logits for gating phase

    const int t = (int)threadIdx.x;
    const int c4 = (t & 15) * 4;         // expert base: 4 experts per thread
    const int r0 = (t >> 4) * 2;         // row base: 2 rows per thread
    const int rowbase = (int)blockIdx.x * BM;

    float acc[2][4] = {{0.f, 0.f, 0.f, 0.f}, {0.f, 0.f, 0.f, 0.f}};

    // staging assignments
    const int xr = t >> 3;               // 0..31 row
    const int xk = (t & 7) * 4;          // 0..28 k offset
    const int we = t >> 2;               // 0..63 expert
    const int wq = (t & 3) * 8;          // kk base {0,8,16,24}

    const float* xp = x + (size_t)(rowbase + xr) * K_DIM + xk;
    const float* wp = w + (size_t)we * K_DIM + wq;

    // register prefetch of chunk 0
    float4 xv  = *(const float4*)(xp);
    float4 wv0 = *(const float4*)(wp);
    float4 wv1 = *(const float4*)(wp + 4);

    for (int k0 = 0; k0 < K_DIM; k0 += KC) {
        // write staged chunk to LDS
        *(float4*)&xs[xr][xk] = xv;
        ws[wq + 0][we] = wv0.x;
        ws[wq + 1][we] = wv0.y;
        ws[wq + 2][we] = wv0.z;
        ws[wq + 3][we] = wv0.w;
        ws[wq + 4][we] = wv1.x;
        ws[wq + 5][we] = wv1.y;
        ws[wq + 6][we] = wv1.z;
        ws[wq + 7][we] = wv1.w;
        __syncthreads();

        // issue next chunk's global loads (latency hides under compute)
        const int kn = (k0 + KC < K_DIM) ? (k0 + KC) : 0;
        xv  = *(const float4*)(xp + kn);
        wv0 = *(const float4*)(wp + kn);
        wv1 = *(const float4*)(wp + kn + 4);

        #pragma unroll
        for (int kk = 0; kk < KC; kk += 4) {
            float4 xa4 = *(const float4*)&xs[r0][kk];
            float4 xb4 = *(const float4*)&xs[r0 + 1][kk];
            const float xa[4] = {xa4.x, xa4.y, xa4.z, xa4.w};
            const float xb[4] = {xb4.x, xb4.y, xb4.z, xb4.w};
            #pragma unroll
            for (int u = 0; u < 4; ++u) {
                float4 wv = *(const float4*)&ws[kk + u][c4];
                acc[0][0] = fmaf(xa[u], wv.x, acc[0][0]);
                acc[0][1] = fmaf(xa[u], wv.y, acc[0][1]);
                acc[0][2] = fmaf(xa[u], wv.z, acc[0][2]);
                acc[0][3] = fmaf(xa[u], wv.w, acc[0][3]);
                acc[1][0] = fmaf(xb[u], wv.x, acc[1][0]);
                acc[1][1] = fmaf(xb[u], wv.y, acc[1][1]);
                acc[1][2] = fmaf(xb[u], wv.z, acc[1][2]);
                acc[1][3] = fmaf(xb[u], wv.w, acc[1][3]);
            }
        }
        __syncthreads();
    }

    // dump logits to LDS for the gating phase
    #pragma unroll
    for (int i = 0; i < 2; ++i)
        #pragma unroll
        for (int j = 0; j < 4; ++j)
            lg[r0 + i][c4 + j] = acc[i][j];
    __syncthreads();

    // gating: one wave per batch of rows; lane == expert
    const int wave = t >> 6;
    const int lane = t & 63;
    #pragma unroll 1
    for (int rr = 0; rr < BM / 4; ++rr) {
        const int r = wave * (BM / 4) + rr;
        const float l = lg[r][lane];

        // row max
        float m = l;
        #pragma unroll
        for (int off = 32; off >= 1; off >>= 1)
            m = fmaxf(m, __shfl_xor(m, off));

        // softmax denom
        float e = expf(l - m);
        float z = e;
        #pragma unroll
        for (int off = 32; off >= 1; off >>= 1)
            z += __shfl_xor(z, off);
        const float p = e / z;

        // top-1 on probs, lowest-index tie-break (matches lax.top_k)
        float v1 = p; int i1 = lane;
        #pragma unroll
        for (int off = 32; off >= 1; off >>= 1) {
            float ov = __shfl_xor(v1, off);
            int   oi = __shfl_xor(i1, off);
            if (ov > v1 || (ov == v1 && oi < i1)) { v1 = ov; i1 = oi; }
        }

        // top-2: mask winner, argmax again
        float v2 = (lane == i1) ? -1.0f : p; int i2 = lane;
        #pragma unroll
        for (int off = 32; off >= 1; off >>= 1) {
            float ov = __shfl_xor(v2, off);
            int   oi = __shfl_xor(i2, off);
            if (ov > v2 || (ov == v2 && oi < i2)) { v2 = ov; i2 = oi; }
        }

        if (lane == 0) {
            const size_t row = (size_t)rowbase + r;
            const float denom = v1 + v2 + 1e-9f;
            out[row * 2 + 0] = v1 / denom;
            out[row * 2 + 1] = v2 / denom;
            out[(size_t)M * 2 + row * 2 + 0] = (float)i1;
            out[(size_t)M * 2 + row * 2 + 1] = (float)i2;
        }
    }
}

extern "C" void kernel_launch(void* const* d_in, const int* in_sizes, int n_in,
                              void* d_out, int out_size, void* d_ws, size_t ws_size,
                              hipStream_t stream)
{
    const float* x = (const float*)d_in[0];
    const float* w = (const float*)d_in[1];
    float* out = (float*)d_out;
    const int M = in_sizes[0] / K_DIM;   // 4*4096 = 16384 rows
    const int grid = M / BM;             // 512 blocks
    top2gating_kernel<<<grid, 256, 0, stream>>>(x, w, out, M);
}